// Round 1
// baseline (507.665 us; speedup 1.0000x reference)
//
#include <hip/hip_runtime.h>
#include <math.h>

// AutoCorrelation: per (b,l) position, circular correlation of q,k along d=512
// via packed complex FFT, top-7 mean, sigmoid blend of v and roll(v,-1,axis=L).
// B=32, L=2048, D=512. One 64-lane wave per position; Stockham radix-2 FFT in LDS.

#define FFT_N 512
#define LOGN 9
#define LBITS 11   // L = 2048
#define LMASK 2047

// Stockham DIF FFT, out-of-place per stage, ping-pong x<->y.
// tw[r] = e^{-2*pi*i*r/N}. SIGN=-1: forward (use tw), SIGN=+1: inverse (conj tw).
// Verified index algebra: stage s has m=2^s, half-len product l2*m = N/2 const;
// butterfly t in [0,256): reads x[t], x[t+256]; twiddle index j*m = t & ~(m-1);
// writes y[t + jm], y[t + jm + m]. Result in natural order after LOGN stages.
template<int SIGN>
__device__ __forceinline__ float2* fft_stages(float2* x, float2* y,
                                              const float2* tw, int lane) {
  int m = 1;
#pragma unroll
  for (int s = 0; s < LOGN; ++s) {
    __syncthreads();
#pragma unroll
    for (int it = 0; it < 4; ++it) {
      const int t = lane + 64 * it;
      const int jm = t & ~(m - 1);
      const float2 c0 = x[t];
      const float2 c1 = x[t + FFT_N / 2];
      const float2 w = tw[jm];
      const float wx = w.x;
      const float wy = (SIGN < 0) ? w.y : -w.y;
      float2 s0;
      s0.x = c0.x + c1.x;
      s0.y = c0.y + c1.y;
      const float dx = c0.x - c1.x;
      const float dy = c0.y - c1.y;
      float2 s1;
      s1.x = dx * wx - dy * wy;
      s1.y = dx * wy + dy * wx;
      y[t + jm] = s0;
      y[t + jm + m] = s1;
    }
    float2* tswap = x; x = y; y = tswap;
    m <<= 1;
  }
  __syncthreads();
  return x;  // buffer holding the result
}

extern "C" __global__ void __launch_bounds__(64)
autocorr_kernel(const float* __restrict__ q, const float* __restrict__ k,
                const float* __restrict__ v, float* __restrict__ out) {
  __shared__ float2 bufA[FFT_N];
  __shared__ float2 bufB[FFT_N];
  __shared__ float2 tw[FFT_N / 2];

  const int lane = (int)threadIdx.x;
  const int p = (int)blockIdx.x;           // position index in [0, B*L)
  const int b = p >> LBITS;
  const int l = p & LMASK;
  const size_t base = (size_t)p * FFT_N;

  // ---- twiddle table: tw[r] = e^{-2 pi i r / N}, r = 0..255 ----
#pragma unroll
  for (int i = 0; i < 4; ++i) {
    const int r = lane + 64 * i;
    const float ang = (float)(2.0 * M_PI / FFT_N) * (float)r;
    float sv, cv;
    sincosf(ang, &sv, &cv);
    tw[r].x = cv;
    tw[r].y = -sv;
  }

  // ---- load z = q + i*k (float4-vectorized, coalesced) ----
  const float4* q4 = (const float4*)(q + base);
  const float4* k4 = (const float4*)(k + base);
#pragma unroll
  for (int h = 0; h < 2; ++h) {
    const int g = lane + 64 * h;           // float4 index; complex base 4g
    const float4 qv = q4[g];
    const float4 kv = k4[g];
    bufA[4 * g + 0] = make_float2(qv.x, kv.x);
    bufA[4 * g + 1] = make_float2(qv.y, kv.y);
    bufA[4 * g + 2] = make_float2(qv.z, kv.z);
    bufA[4 * g + 3] = make_float2(qv.w, kv.w);
  }

  // ---- forward FFT of packed z ----
  float2* Z = fft_stages<-1>(bufA, bufB, tw, lane);
  float2* S = (Z == bufA) ? bufB : bufA;

  // ---- Hermitian split + S = Q * conj(K), scale (1/4 split * 1/N ifft) ----
  const float sc = 0.25f / (float)FFT_N;
#pragma unroll
  for (int i = 0; i < 8; ++i) {
    const int f = lane + 64 * i;
    const float2 A = Z[f];
    const float2 Bc = Z[(FFT_N - f) & (FFT_N - 1)];
    // A = Q + iK, conj(Bc) = Q - iK  (q,k real)
    const float sr = sc * ((A.x + Bc.x) * (A.y + Bc.y) - (A.y - Bc.y) * (A.x - Bc.x));
    const float si = sc * ((A.x * A.x - Bc.x * Bc.x) + (A.y * A.y - Bc.y * Bc.y));
    S[f] = make_float2(sr, si);
  }
  // (sync at top of next fft_stages covers the S writes)

  // ---- inverse FFT (conjugate twiddles); corr[n] = C[n].x ----
  float2* C = fft_stages<1>(S, Z, tw, lane);

  // ---- pull corr into registers in float4-friendly layout ----
  float vals[8];
#pragma unroll
  for (int j = 0; j < 4; ++j) {
    vals[j]     = C[4 * lane + j].x;
    vals[4 + j] = C[FFT_N / 2 + 4 * lane + j].x;
  }

  // issue v / v_rolled loads now; top-k reduction hides the latency
  const float4* v4 = (const float4*)(v + base);
  const int pn = (b << LBITS) | ((l + 1) & LMASK);
  const float4* vn4 = (const float4*)(v + (size_t)pn * FFT_N);
  const float4 va0 = v4[lane];
  const float4 va1 = v4[lane + 64];
  const float4 vb0 = vn4[lane];
  const float4 vb1 = vn4[lane + 64];

  // ---- top-7 mean over the 512 corr values (wave-wide) ----
  float tmp[8];
#pragma unroll
  for (int i = 0; i < 8; ++i) tmp[i] = vals[i];
  float ssum = 0.0f;
  for (int r = 0; r < 7; ++r) {
    float mloc = tmp[0];
#pragma unroll
    for (int i = 1; i < 8; ++i) mloc = fmaxf(mloc, tmp[i]);
    float g = mloc;
#pragma unroll
    for (int off = 32; off >= 1; off >>= 1) g = fmaxf(g, __shfl_xor(g, off));
    ssum += g;
    const unsigned long long ball = __ballot(mloc == g);
    const int firstlane = (int)__ffsll(ball) - 1;
    if (lane == firstlane) {
      bool done = false;
#pragma unroll
      for (int i = 0; i < 8; ++i) {
        if (!done && tmp[i] == g) { tmp[i] = -1e30f; done = true; }
      }
    }
  }
  const float mean = ssum * (1.0f / 7.0f);

  // ---- epilogue: out = v + (v_next - v) * sigmoid(mean - corr) ----
  float4* o4 = (float4*)(out + base);
  {
    float4 o;
    float w1;
    w1 = 1.0f / (1.0f + __expf(vals[0] - mean)); o.x = va0.x + (vb0.x - va0.x) * w1;
    w1 = 1.0f / (1.0f + __expf(vals[1] - mean)); o.y = va0.y + (vb0.y - va0.y) * w1;
    w1 = 1.0f / (1.0f + __expf(vals[2] - mean)); o.z = va0.z + (vb0.z - va0.z) * w1;
    w1 = 1.0f / (1.0f + __expf(vals[3] - mean)); o.w = va0.w + (vb0.w - va0.w) * w1;
    o4[lane] = o;
    w1 = 1.0f / (1.0f + __expf(vals[4] - mean)); o.x = va1.x + (vb1.x - va1.x) * w1;
    w1 = 1.0f / (1.0f + __expf(vals[5] - mean)); o.y = va1.y + (vb1.y - va1.y) * w1;
    w1 = 1.0f / (1.0f + __expf(vals[6] - mean)); o.z = va1.z + (vb1.z - va1.z) * w1;
    w1 = 1.0f / (1.0f + __expf(vals[7] - mean)); o.w = va1.w + (vb1.w - va1.w) * w1;
    o4[lane + 64] = o;
  }
}

extern "C" void kernel_launch(void* const* d_in, const int* in_sizes, int n_in,
                              void* d_out, int out_size, void* d_ws, size_t ws_size,
                              hipStream_t stream) {
  const float* q = (const float*)d_in[0];
  const float* k = (const float*)d_in[1];
  const float* v = (const float*)d_in[2];
  float* out = (float*)d_out;
  const int positions = 32 * 2048;  // B * L
  autocorr_kernel<<<dim3(positions), dim3(64), 0, stream>>>(q, k, v, out);
}

// Round 2
// 444.107 us; speedup vs baseline: 1.1431x; 1.1431x over previous
//
#include <hip/hip_runtime.h>
#include <math.h>

// AutoCorrelation, register-resident FFT version.
// Per (b,l) position: circular correlation of q,k along d=512 via packed
// complex FFT, top-7 mean, sigmoid blend of v and roll(v,-1,axis=L).
// B=32, L=2048, D=512. One wave per position, 4 waves/block, NO LDS, no barriers.
// FFT-512 = DFT8 (in-register, n2=reg) x DFT64 (across lanes, shfl_xor butterflies).
// Layout: element n lives at lane (n & 63), register (n >> 6).

#define LBITS 11   // L = 2048
#define LMASK 2047

typedef float2 cplx;

__device__ __forceinline__ cplx cmul(cplx a, cplx b) {
  return make_float2(a.x * b.x - a.y * b.y, a.x * b.y + a.y * b.x);
}
__device__ __forceinline__ cplx cadd(cplx a, cplx b) {
  return make_float2(a.x + b.x, a.y + b.y);
}
__device__ __forceinline__ cplx csub(cplx a, cplx b) {
  return make_float2(a.x - b.x, a.y - b.y);
}
__device__ __forceinline__ cplx csel(bool c, cplx a, cplx b) {
  return make_float2(c ? a.x : b.x, c ? a.y : b.y);
}
// multiply by (0, S) i.e. S*i  (S = +/-1)
__device__ __forceinline__ cplx cmuli(cplx a, float S) {
  return make_float2(-S * a.y, S * a.x);
}

__device__ __forceinline__ int bitrev6(int x) {
  return (int)(__brev((unsigned)x) >> 26);
}

// 8-point DFT over registers, natural order in AND out.
// SIGN = -1 forward (W8 = e^{-2pi i/8}), +1 inverse (unscaled).
template<int SIGN>
__device__ __forceinline__ void dft8(cplx* x) {
  const float R = 0.70710678118654752f;
  const float S = (float)SIGN;
  // stage m=4 (DIF), twiddles W8^j on the diff leg
  cplx t0 = cadd(x[0], x[4]), t4 = csub(x[0], x[4]);
  cplx t1 = cadd(x[1], x[5]), d1 = csub(x[1], x[5]);
  cplx t2 = cadd(x[2], x[6]), d2 = csub(x[2], x[6]);
  cplx t3 = cadd(x[3], x[7]), d3 = csub(x[3], x[7]);
  cplx t5 = cmul(d1, make_float2(R, S * R));    // W8^1
  cplx t6 = cmuli(d2, S);                        // W8^2
  cplx t7 = cmul(d3, make_float2(-R, S * R));   // W8^3
  // stage m=2, twiddles W4^j
  cplx u0 = cadd(t0, t2), u2 = csub(t0, t2);
  cplx u1 = cadd(t1, t3), u3 = cmuli(csub(t1, t3), S);
  cplx u4 = cadd(t4, t6), u6 = csub(t4, t6);
  cplx u5 = cadd(t5, t7), u7 = cmuli(csub(t5, t7), S);
  // stage m=1
  cplx v0 = cadd(u0, u1), v1 = csub(u0, u1);
  cplx v2 = cadd(u2, u3), v3 = csub(u2, u3);
  cplx v4 = cadd(u4, u5), v5 = csub(u4, u5);
  cplx v6 = cadd(u6, u7), v7 = csub(u6, u7);
  // undo bitrev3 (compile-time register rename)
  x[0] = v0; x[1] = v4; x[2] = v2; x[3] = v6;
  x[4] = v1; x[5] = v5; x[6] = v3; x[7] = v7;
}

// 64-point DIF FFT across lanes (forward, natural lane order in,
// bit-reversed lane order out: lane r holds X64[bitrev6(r)]).
__device__ __forceinline__ void lane_fft64_dif_fwd(cplx* v, int lane) {
#pragma unroll
  for (int s = 5; s >= 0; --s) {
    const int m = 1 << s;
    const bool hi = (lane & m) != 0;
    float sn, cs;
    __sincosf(-(float)M_PI / (float)m * (float)(lane & (m - 1)), &sn, &cs);
    const cplx w = make_float2(cs, sn);
#pragma unroll
    for (int j = 0; j < 8; ++j) {
      cplx x = v[j], p;
      p.x = __shfl_xor(x.x, m);
      p.y = __shfl_xor(x.y, m);
      cplx sum = cadd(x, p);
      cplx dif = csub(p, x);   // (a - b) on the hi lane
      v[j] = csel(hi, cmul(dif, w), sum);
    }
  }
}

// 64-point DIT inverse FFT across lanes (input lane-bit-reversed,
// output natural lane order; unscaled).
__device__ __forceinline__ void lane_fft64_dit_inv(cplx* v, int lane) {
#pragma unroll
  for (int s = 0; s <= 5; ++s) {
    const int m = 1 << s;
    const bool hi = (lane & m) != 0;
    float sn, cs;
    __sincosf((float)M_PI / (float)m * (float)(lane & (m - 1)), &sn, &cs);
    const cplx w = make_float2(cs, sn);
#pragma unroll
    for (int j = 0; j < 8; ++j) {
      cplx x = v[j], p;
      p.x = __shfl_xor(x.x, m);
      p.y = __shfl_xor(x.y, m);
      cplx even = csel(hi, p, x);
      cplx odd  = csel(hi, x, p);
      cplx t = cmul(odd, w);
      v[j] = csel(hi, csub(even, t), cadd(even, t));
    }
  }
}

extern "C" __global__ void __launch_bounds__(256)
autocorr_kernel(const float* __restrict__ q, const float* __restrict__ k,
                const float* __restrict__ vv, float* __restrict__ out) {
  const int lane = (int)threadIdx.x & 63;
  const int wid = (int)threadIdx.x >> 6;
  const int p = (int)blockIdx.x * 4 + wid;   // position in [0, B*L)
  const int b = p >> LBITS;
  const int l = p & LMASK;
  const size_t base = (size_t)p * 512;

  // ---- load z = q + i*k in layout n = lane + 64*j (coalesced dwords) ----
  cplx v[8];
#pragma unroll
  for (int j = 0; j < 8; ++j) {
    const int n = lane + 64 * j;
    v[j] = make_float2(q[base + n], k[base + n]);
  }

  // ---- forward FFT-512 ----
  dft8<-1>(v);  // over regs, natural k2
  {   // per-lane twiddle W512^{lane*k2} (negative exponent)
    float sn, cs;
    __sincosf(-2.0f * (float)M_PI * (float)lane / 512.0f, &sn, &cs);
    const cplx bw = make_float2(cs, sn);
    cplx w = bw;
#pragma unroll
    for (int j = 1; j < 8; ++j) { v[j] = cmul(v[j], w); w = cmul(w, bw); }
  }
  lane_fft64_dif_fwd(v, lane);
  // now v[k2] on lane r = Z[k2 + 8*bitrev6(r)]

  // ---- Hermitian partners Z[N-f] ----
  cplx Bc[8];
#pragma unroll
  for (int k2 = 1; k2 < 8; ++k2) {
    Bc[k2].x = __shfl_xor(v[8 - k2].x, 63);
    Bc[k2].y = __shfl_xor(v[8 - k2].y, 63);
  }
  {
    const int src = bitrev6((64 - bitrev6(lane)) & 63);
    Bc[0].x = __shfl(v[0].x, src);
    Bc[0].y = __shfl(v[0].y, src);
  }

  // ---- S = Q * conj(K) with Hermitian split; sc folds 1/4 and 1/N ----
  const float sc = 0.25f / 512.0f;
#pragma unroll
  for (int j = 0; j < 8; ++j) {
    const cplx A = v[j], B = Bc[j];
    const float sr = sc * ((A.x + B.x) * (A.y + B.y) - (A.y - B.y) * (A.x - B.x));
    const float si = sc * ((A.x * A.x - B.x * B.x) + (A.y * A.y - B.y * B.y));
    v[j] = make_float2(sr, si);
  }

  // ---- inverse FFT-512 ----
  lane_fft64_dit_inv(v, lane);
  {   // per-lane twiddle W512^{-lane*k2} conj = positive exponent
    float sn, cs;
    __sincosf(2.0f * (float)M_PI * (float)lane / 512.0f, &sn, &cs);
    const cplx bw = make_float2(cs, sn);
    cplx w = bw;
#pragma unroll
    for (int j = 1; j < 8; ++j) { v[j] = cmul(v[j], w); w = cmul(w, bw); }
  }
  dft8<1>(v);
  // corr[lane + 64*j] = v[j].x

  float vals[8];
#pragma unroll
  for (int j = 0; j < 8; ++j) vals[j] = v[j].x;

  // ---- issue v / v_rolled loads; top-k hides the latency ----
  const int pn = (b << LBITS) | ((l + 1) & LMASK);
  const size_t basen = (size_t)pn * 512;
  float va[8], vb[8];
#pragma unroll
  for (int j = 0; j < 8; ++j) {
    const int n = lane + 64 * j;
    va[j] = vv[base + n];
    vb[j] = vv[basen + n];
  }

  // ---- top-7 mean over 512 corr values (wave-wide) ----
  float tmp[8];
#pragma unroll
  for (int i = 0; i < 8; ++i) tmp[i] = vals[i];
  float ssum = 0.0f;
  for (int r = 0; r < 7; ++r) {
    float mloc = tmp[0];
#pragma unroll
    for (int i = 1; i < 8; ++i) mloc = fmaxf(mloc, tmp[i]);
    float g = mloc;
#pragma unroll
    for (int off = 32; off >= 1; off >>= 1) g = fmaxf(g, __shfl_xor(g, off));
    ssum += g;
    const unsigned long long ball = __ballot(mloc == g);
    const int firstlane = (int)__ffsll(ball) - 1;
    if (lane == firstlane) {
      bool done = false;
#pragma unroll
      for (int i = 0; i < 8; ++i) {
        if (!done && tmp[i] == g) { tmp[i] = -1e30f; done = true; }
      }
    }
  }
  const float mean = ssum * (1.0f / 7.0f);

  // ---- epilogue: out = v + (v_next - v) * sigmoid(mean - corr) ----
#pragma unroll
  for (int j = 0; j < 8; ++j) {
    const float w1 = 1.0f / (1.0f + __expf(vals[j] - mean));
    out[base + lane + 64 * j] = va[j] + (vb[j] - va[j]) * w1;
  }
}

extern "C" void kernel_launch(void* const* d_in, const int* in_sizes, int n_in,
                              void* d_out, int out_size, void* d_ws, size_t ws_size,
                              hipStream_t stream) {
  const float* q = (const float*)d_in[0];
  const float* k = (const float*)d_in[1];
  const float* v = (const float*)d_in[2];
  float* out = (float*)d_out;
  const int positions = 32 * 2048;            // B * L
  autocorr_kernel<<<dim3(positions / 4), dim3(256), 0, stream>>>(q, k, v, out);
}

// Round 3
// 401.623 us; speedup vs baseline: 1.2640x; 1.1058x over previous
//
#include <hip/hip_runtime.h>
#include <math.h>

// AutoCorrelation, register-resident FFT, round 2: branch-free butterflies,
// DPP/swizzle shuffles with zero address math, divergence-free top-7.
// Per (b,l): circular corr of q,k along d=512 via packed complex FFT,
// top-7 mean, sigmoid blend of v and roll(v,-1,axis=1).
// FFT-512 = DFT8 (regs) x DFT64 (lanes). Element n at lane (n&63), reg (n>>6).

#define LBITS 11   // L = 2048
#define LMASK 2047

typedef float2 cplx;

__device__ __forceinline__ cplx cmul(cplx a, cplx b) {
  return make_float2(fmaf(a.x, b.x, -(a.y * b.y)), fmaf(a.x, b.y, a.y * b.x));
}
__device__ __forceinline__ cplx cadd(cplx a, cplx b) {
  return make_float2(a.x + b.x, a.y + b.y);
}
__device__ __forceinline__ cplx csub(cplx a, cplx b) {
  return make_float2(a.x - b.x, a.y - b.y);
}
// multiply by S*i  (S = +/-1)
__device__ __forceinline__ cplx cmuli(cplx a, float S) {
  return make_float2(-S * a.y, S * a.x);
}

__device__ __forceinline__ int bitrev6(int x) {
  return (int)(__brev((unsigned)x) >> 26);
}

// ---- lane exchange lane^M: DPP for 1,2; ds_swizzle imm for 4,8,16; bpermute 32 ----
template<int M>
__device__ __forceinline__ float shx(float x, int a32) {
  const int xi = __float_as_int(x);
  int r;
  if constexpr (M == 1)
    r = __builtin_amdgcn_update_dpp(xi, xi, 0xB1, 0xF, 0xF, false);  // quad_perm 1,0,3,2
  else if constexpr (M == 2)
    r = __builtin_amdgcn_update_dpp(xi, xi, 0x4E, 0xF, 0xF, false);  // quad_perm 2,3,0,1
  else if constexpr (M == 4)
    r = __builtin_amdgcn_ds_swizzle(xi, 0x101F);
  else if constexpr (M == 8)
    r = __builtin_amdgcn_ds_swizzle(xi, 0x201F);
  else if constexpr (M == 16)
    r = __builtin_amdgcn_ds_swizzle(xi, 0x401F);
  else
    r = __builtin_amdgcn_ds_bpermute(a32, xi);
  return __int_as_float(r);
}

// 8-point DFT over registers, natural order in and out. SIGN=-1 fwd, +1 inv.
template<int SIGN>
__device__ __forceinline__ void dft8(cplx* x) {
  const float R = 0.70710678118654752f;
  const float S = (float)SIGN;
  cplx t0 = cadd(x[0], x[4]), t4 = csub(x[0], x[4]);
  cplx t1 = cadd(x[1], x[5]), d1 = csub(x[1], x[5]);
  cplx t2 = cadd(x[2], x[6]), d2 = csub(x[2], x[6]);
  cplx t3 = cadd(x[3], x[7]), d3 = csub(x[3], x[7]);
  cplx t5 = cmul(d1, make_float2(R, S * R));
  cplx t6 = cmuli(d2, S);
  cplx t7 = cmul(d3, make_float2(-R, S * R));
  cplx u0 = cadd(t0, t2), u2 = csub(t0, t2);
  cplx u1 = cadd(t1, t3), u3 = cmuli(csub(t1, t3), S);
  cplx u4 = cadd(t4, t6), u6 = csub(t4, t6);
  cplx u5 = cadd(t5, t7), u7 = cmuli(csub(t5, t7), S);
  cplx v0 = cadd(u0, u1), v1 = csub(u0, u1);
  cplx v2 = cadd(u2, u3), v3 = csub(u2, u3);
  cplx v4 = cadd(u4, u5), v5 = csub(u4, u5);
  cplx v6 = cadd(u6, u7), v7 = csub(u6, u7);
  x[0] = v0; x[1] = v4; x[2] = v2; x[3] = v6;
  x[4] = v1; x[5] = v5; x[6] = v3; x[7] = v7;
}

// Forward DIF stage: lo: x+p ; hi: (p-x)*w.   pre = p + sgn*x ; out = pre*weff.
template<int M>
__device__ __forceinline__ void fwd_stage(cplx* v, float2 weff, float sgn, int a32) {
#pragma unroll
  for (int j = 0; j < 8; ++j) {
    const float px = shx<M>(v[j].x, a32);
    const float py = shx<M>(v[j].y, a32);
    const float prx = fmaf(v[j].x, sgn, px);
    const float pry = fmaf(v[j].y, sgn, py);
    if constexpr (M == 1) {
      v[j] = make_float2(prx, pry);                      // w == 1
    } else {
      v[j] = make_float2(fmaf(prx, weff.x, -(pry * weff.y)),
                         fmaf(prx, weff.y, pry * weff.x));
    }
  }
}

// Inverse DIT stage (conj twiddle): u = x*conj(weff); out = shfl(u) + sgn*u.
template<int M>
__device__ __forceinline__ void inv_stage(cplx* v, float2 weff, float sgn, int a32) {
#pragma unroll
  for (int j = 0; j < 8; ++j) {
    float ux, uy;
    if constexpr (M == 1) {
      ux = v[j].x; uy = v[j].y;                          // w == 1
    } else {
      ux = fmaf(v[j].x, weff.x, v[j].y * weff.y);
      uy = fmaf(v[j].y, weff.x, -(v[j].x * weff.y));
    }
    const float px = shx<M>(ux, a32);
    const float py = shx<M>(uy, a32);
    v[j] = make_float2(fmaf(ux, sgn, px), fmaf(uy, sgn, py));
  }
}

// Wave(64)-wide max via DPP row_shr/row_bcast; result broadcast from lane 63.
__device__ __forceinline__ float wave_max63(float v) {
#define DPP_MAX(ctrl)                                                        \
  v = fmaxf(v, __int_as_float(__builtin_amdgcn_update_dpp(                   \
                   __float_as_int(v), __float_as_int(v), ctrl, 0xF, 0xF, false)));
  DPP_MAX(0x111)  // row_shr:1
  DPP_MAX(0x112)  // row_shr:2
  DPP_MAX(0x114)  // row_shr:4
  DPP_MAX(0x118)  // row_shr:8
  DPP_MAX(0x142)  // row_bcast15
  DPP_MAX(0x143)  // row_bcast31
#undef DPP_MAX
  return __int_as_float(__builtin_amdgcn_readlane(__float_as_int(v), 63));
}

extern "C" __global__ void __launch_bounds__(256)
autocorr_kernel(const float* __restrict__ q, const float* __restrict__ k,
                const float* __restrict__ vv, float* __restrict__ out) {
  const int lane = (int)threadIdx.x & 63;
  const int wid = (int)threadIdx.x >> 6;
  const int p = (int)blockIdx.x * 4 + wid;
  const int b = p >> LBITS;
  const int l = p & LMASK;
  const size_t base = (size_t)p * 512;

  // ---- precomputed shuffle addresses (bytes) ----
  const int a32 = ((lane ^ 32) << 2);
  const int a63 = ((lane ^ 63) << 2);
  const int a0h = (bitrev6((64 - bitrev6(lane)) & 63) << 2);  // Hermitian partner, reg 0

  // ---- per-stage twiddles weff_m = (lane&m)? e^{-i pi (lane&(m-1))/m} : 1 ----
  float2 w32, w16, w8, w4, w2;
  {
    float sn, cs;
#define MKW(dst, m)                                                          \
    __sincosf(-(float)M_PI * (float)(lane & ((m)-1)) / (float)(m), &sn, &cs);\
    dst = (lane & (m)) ? make_float2(cs, sn) : make_float2(1.0f, 0.0f);
    MKW(w32, 32) MKW(w16, 16) MKW(w8, 8) MKW(w4, 4) MKW(w2, 2)
#undef MKW
  }
  const float s32 = (lane & 32) ? -1.0f : 1.0f;
  const float s16 = (lane & 16) ? -1.0f : 1.0f;
  const float s8  = (lane & 8)  ? -1.0f : 1.0f;
  const float s4  = (lane & 4)  ? -1.0f : 1.0f;
  const float s2  = (lane & 2)  ? -1.0f : 1.0f;
  const float s1  = (lane & 1)  ? -1.0f : 1.0f;

  // ---- load z = q + i*k, layout n = lane + 64*j ----
  cplx v[8];
#pragma unroll
  for (int j = 0; j < 8; ++j) {
    const int n = lane + 64 * j;
    v[j] = make_float2(q[base + n], k[base + n]);
  }

  // ---- forward FFT-512: dft8, base twiddle W512^{lane*j}, 6 lane stages ----
  dft8<-1>(v);
  float2 bw;
  {
    float sn, cs;
    __sincosf(-2.0f * (float)M_PI * (float)lane / 512.0f, &sn, &cs);
    bw = make_float2(cs, sn);
    cplx w = bw;
#pragma unroll
    for (int j = 1; j < 8; ++j) { v[j] = cmul(v[j], w); w = cmul(w, bw); }
  }
  fwd_stage<32>(v, w32, s32, a32);
  fwd_stage<16>(v, w16, s16, a32);
  fwd_stage<8>(v, w8, s8, a32);
  fwd_stage<4>(v, w4, s4, a32);
  fwd_stage<2>(v, w2, s2, a32);
  fwd_stage<1>(v, w2, s1, a32);
  // v[k2] on lane r = Z[k2 + 8*bitrev6(r)]

  // ---- Hermitian partners Z[N-f] ----
  cplx Bc[8];
#pragma unroll
  for (int k2 = 1; k2 < 8; ++k2) {
    Bc[k2].x = __int_as_float(__builtin_amdgcn_ds_bpermute(a63, __float_as_int(v[8 - k2].x)));
    Bc[k2].y = __int_as_float(__builtin_amdgcn_ds_bpermute(a63, __float_as_int(v[8 - k2].y)));
  }
  Bc[0].x = __int_as_float(__builtin_amdgcn_ds_bpermute(a0h, __float_as_int(v[0].x)));
  Bc[0].y = __int_as_float(__builtin_amdgcn_ds_bpermute(a0h, __float_as_int(v[0].y)));

  // ---- S = Q*conj(K) via Hermitian split; sc folds 1/4 and 1/N ----
  const float sc = 0.25f / 512.0f;
#pragma unroll
  for (int j = 0; j < 8; ++j) {
    const cplx A = v[j], B = Bc[j];
    const float t1 = A.x + B.x, t2 = A.y + B.y, t3 = A.y - B.y, t4 = A.x - B.x;
    const float sr = sc * fmaf(t1, t2, -(t3 * t4));
    float si = fmaf(A.x, A.x, -(B.x * B.x));
    si = fmaf(A.y, A.y, si);
    si = fmaf(-B.y, B.y, si);
    v[j] = make_float2(sr, sc * si);
  }

  // ---- inverse FFT-512 ----
  inv_stage<1>(v, w2, s1, a32);
  inv_stage<2>(v, w2, s2, a32);
  inv_stage<4>(v, w4, s4, a32);
  inv_stage<8>(v, w8, s8, a32);
  inv_stage<16>(v, w16, s16, a32);
  inv_stage<32>(v, w32, s32, a32);
  {
    const float2 bwc = make_float2(bw.x, -bw.y);
    cplx w = bwc;
#pragma unroll
    for (int j = 1; j < 8; ++j) { v[j] = cmul(v[j], w); w = cmul(w, bwc); }
  }
  dft8<1>(v);
  // corr[lane + 64*j] = v[j].x

  float vals[8];
#pragma unroll
  for (int j = 0; j < 8; ++j) vals[j] = v[j].x;

  // ---- issue v / v_rolled loads; top-7 hides the latency ----
  const int pn = (b << LBITS) | ((l + 1) & LMASK);
  const size_t basen = (size_t)pn * 512;
  float va[8], vb[8];
#pragma unroll
  for (int j = 0; j < 8; ++j) {
    const int n = lane + 64 * j;
    va[j] = vv[base + n];
    vb[j] = vv[basen + n];
  }

  // ---- top-7 mean: descending bound chain, divergence-free ----
  float lm = vals[0];
#pragma unroll
  for (int i = 1; i < 8; ++i) lm = fmaxf(lm, vals[i]);
  float g = wave_max63(lm);
  float ssum = g;
  float bound = g;
#pragma unroll
  for (int r = 1; r < 7; ++r) {
    lm = -1e30f;
#pragma unroll
    for (int i = 0; i < 8; ++i) {
      const float c = (vals[i] < bound) ? vals[i] : -1e30f;
      lm = fmaxf(lm, c);
    }
    g = wave_max63(lm);
    ssum += g;
    bound = g;
  }
  const float mean = ssum * (1.0f / 7.0f);

  // ---- epilogue: out = va + (vb - va) * sigmoid(mean - corr) ----
#pragma unroll
  for (int j = 0; j < 8; ++j) {
    const float w1 = 1.0f / (1.0f + __expf(vals[j] - mean));
    out[base + lane + 64 * j] = fmaf(vb[j] - va[j], w1, va[j]);
  }
}

extern "C" void kernel_launch(void* const* d_in, const int* in_sizes, int n_in,
                              void* d_out, int out_size, void* d_ws, size_t ws_size,
                              hipStream_t stream) {
  const float* q = (const float*)d_in[0];
  const float* k = (const float*)d_in[1];
  const float* v = (const float*)d_in[2];
  float* out = (float*)d_out;
  const int positions = 32 * 2048;  // B * L
  autocorr_kernel<<<dim3(positions / 4), dim3(256), 0, stream>>>(q, k, v, out);
}